// Round 14
// baseline (87.739 us; speedup 1.0000x reference)
//
#include <hip/hip_runtime.h>

#define NRAYS 4096
#define NSTEPS 160
#define NSAMP (NRAYS*NSTEPS)
#define GG 160
#define GG2 (GG*GG)
#define GG3 (GG*GG2)
#define GM 80
#define GM2 (GM*GM)

#define NEARV 0.05f
#define DISTV 0.00625f
#define SVAL 80.0f
#define ACT_SHIFT_C (-9.2102403669758813f)
#define INV2H 40.0f          // 1/(2*VOXEL_SIZE)
#define MASK_THRES_C 1e-3f
#define FAST_THRES_C 1e-7f

// normalized 5-tap gaussian, sigma=1
#define KW0 0.05448868454964295f
#define KW1 0.24420134200323332f
#define KW2 0.40261994689424750f

__device__ __forceinline__ float sigmf(float x){ return 1.0f/(1.0f+__expf(-x)); }
__device__ __forceinline__ float softplusf_(float x){ return (x>20.0f)? x : log1pf(__expf(x)); }

__device__ __forceinline__ float kwf(int i){
  float r = 0.0f;
  r = (i==0)?KW0:r; r=(i==1)?KW1:r; r=(i==2)?KW2:r; r=(i==3)?KW1:r; r=(i==4)?KW0:r;
  return r;
}

__device__ __forceinline__ void tricoord(float p, int Gx, int& i0, float& fr){
  float u = (p + 1.0f)*0.5f*(float)(Gx-1);
  u = fminf(fmaxf(u, 0.0f), (float)(Gx-1));
  int i = (int)floorf(u);
  i = min(max(i,0), Gx-2);
  i0 = i; fr = u - (float)i;
}

// ---------------- fused y+z gaussian passes (zero-pad SAME), LDS tiled ----------------
// block 0 additionally zero-inits out rgb and cnt[0..1] (stream-ordered before consumers).
__global__ __launch_bounds__(256) void ksmooth_yz(const float* __restrict__ in, float* __restrict__ out,
                                                  float* __restrict__ outbuf, int* __restrict__ cnt){
  __shared__ float S[36][37];
  __shared__ float Tz[36][33];
  const int bx = blockIdx.x;          // 160 * 25
  const int t = threadIdx.x;
  if (bx == 0){
    for (int i = t; i < NRAYS*3; i += 256) outbuf[i] = 0.0f;
    if (t < 2) cnt[t] = 0;
  }
  const int x  = bx / 25;
  const int tile = bx % 25;
  const int Y0 = (tile/5)*32, Z0 = (tile%5)*32;
  const float kw[5] = {KW0,KW1,KW2,KW1,KW0};
  for (int i = t; i < 36*36; i += 256){
    int r = i/36, c = i - (i/36)*36;
    int y = Y0 + r - 2, z = Z0 + c - 2;
    float v = 0.0f;
    if (y>=0 && y<GG && z>=0 && z<GG) v = in[(x*GG+y)*GG+z];
    S[r][c] = v;
  }
  __syncthreads();
  for (int i = t; i < 36*32; i += 256){
    int r = i >> 5, c = i & 31;
    float acc = 0.f;
    #pragma unroll
    for (int d=0; d<5; d++) acc += kw[d]*S[r][c+d];
    Tz[r][c] = acc;
  }
  __syncthreads();
  for (int i = t; i < 32*32; i += 256){
    int yy = i >> 5, c = i & 31;
    float acc = 0.f;
    #pragma unroll
    for (int d=0; d<5; d++) acc += kw[d]*Tz[yy+d][c];
    out[(x*GG + Y0+yy)*GG + Z0 + c] = acc;
  }
}

// ---------------- wave-per-ray march: lanes cooperate on ONE step's 88 loads ----------------
// Exactly the serial step set (no speculation). Per step: lane-split loads (R rows 32,
// Ey 24, mask 8; Ez 24 in batch 2) with closed-form per-lane weights, then one
// 64-lane butterfly reduce of {sdf,gx,gy,gz,dens}. Summation order differs from the
// serial nested loops only by reassociation (threshold 3e-2; expected ~1e-5).
// em-partitioned compaction: em=0 ascend from cnt[0], em=1 descend from NSAMP (cnt[1]).
__global__ __launch_bounds__(256) void kmarch_wave(
  const float* __restrict__ ro, const float* __restrict__ rd,
  const float* __restrict__ vd, const int* __restrict__ em,
  const float* __restrict__ maskg, const float* __restrict__ Y,
  int* __restrict__ slist, float* __restrict__ sw, float* __restrict__ sgrad,
  int* __restrict__ cnt, float* __restrict__ out)
{
  const int t = threadIdx.x;
  const int l = t & 63;
  const int n = blockIdx.x*4 + (t>>6);
  if (n >= NRAYS) return;

  const float ox=ro[n*3+0], oy=ro[n*3+1], oz=ro[n*3+2];
  const float dx=rd[n*3+0], dy=rd[n*3+1], dz=rd[n*3+2];
  const float vx=vd[n*3+0], vy=vd[n*3+1], vz=vd[n*3+2];
  const int emn = em[n];

  // ---- per-lane role decode (loop-invariant) ----
  const bool isR = (l < 32);
  const bool isE = (l >= 32 && l < 56);
  const bool isM = (l >= 56);
  const int r_jb = (l>>4)&1, r_jc = (l>>3)&1, r_u = l&7;
  const int e1 = l-32, e_wh = e1/12, e_r = e1%12, e_jc = e_r/6, e_u = e_r%6;
  const int mb = l-56, m_ca=(mb>>2)&1, m_cb=(mb>>1)&1, m_cc=mb&1;
  const bool isZ = (l < 24);
  const int z_wh = l/12, z_r = l%12, z_jb = z_r/6, z_u = z_r%6;

  // loop-invariant conv-tap constants
  const float kA = kwf(r_u-1), kB = kwf(r_u-2), kC = kwf(r_u), kD = kwf(r_u-3);
  const float dG1 = kB - kC, dG2 = kD - kA;     // cgx pieces
  const float kE = kwf(e_u), kF = kwf(e_u-1);   // Ey cxe
  const float kZ1 = kwf(z_u), kZ2 = kwf(z_u-1); // Ez cxe

  float T1=1.0f, T2=1.0f, cum=0.0f;
  for (int s=0; s<NSTEPS; s++){
    const float tt = NEARV + DISTV*(float)s;
    const float px = ox + dx*tt, py = oy + dy*tt, pz = oz + dz*tt;

    int mx,my,mz; float mfx,mfy,mfz;
    tricoord(px, GM, mx, mfx); tricoord(py, GM, my, mfy); tricoord(pz, GM, mz, mfz);
    int ix,iy,iz; float fx,fy,fz;
    tricoord(px, GG, ix, fx); tricoord(py, GG, iy, fy); tricoord(pz, GG, iz, fz);

    const float ax0 = (ix>=1)?1.f:0.f, ax1 = (ix<=GG-3)?1.f:0.f;
    const float by0f = (iy>=1)?1.f:0.f, by1f = (iy<=GG-3)?1.f:0.f;
    const float bz0f = (iz>=1)?1.f:0.f, bz1f = (iz<=GG-3)?1.f:0.f;
    const float wx0=1.f-fx, wx1=fx, wy0=1.f-fy, wy1=fy, wz0=1.f-fz, wz1=fz;

    // ---- batch-1 + batch-2 loads (issued together; per-lane role) ----
    float V1 = 0.0f, V2 = 0.0f;
    if (isR){
      int a = ix-3+r_u;
      if (a>=0 && a<GG) V1 = Y[(a*GG + iy+r_jb)*GG + iz+r_jc];
    } else if (isE){
      int a = ix-2+e_u;
      int b = e_wh ? (iy+2) : (iy-1);
      bool ok = (a>=0 && a<GG) && (e_wh ? (iy<=GG-3) : (iy>=1));
      if (ok) V1 = Y[(a*GG + b)*GG + iz+e_jc];
    } else {
      V1 = maskg[((mx+m_ca)*GM + my+m_cb)*GM + mz+m_cc];
    }
    if (isZ){
      int a = ix-2+z_u;
      int c = z_wh ? (iz+2) : (iz-1);
      bool ok = (a>=0 && a<GG) && (z_wh ? (iz<=GG-3) : (iz>=1));
      if (ok) V2 = Y[(a*GG + iy+z_jb)*GG + c];
    }

    // ---- per-lane weighted partials ----
    float p_sdf=0.f, p_gx=0.f, p_gy=0.f, p_gz=0.f, p_den=0.f;
    if (isR){
      const float wyv = r_jb ? wy1 : wy0;
      const float wzv = r_jc ? wz1 : wz0;
      const float cxs = wx0*kA + wx1*kB;
      const float cgx = wx0*ax0*dG1 + wx1*ax1*dG2;
      const float base = wzv*cxs*INV2H*V1;
      p_sdf = wyv*wzv*cxs*V1;
      p_gx  = wyv*wzv*cgx*V1*INV2H;
      p_gy  = base * (r_jb ? (wy0*by0f) : -(wy1*by1f));
      p_gz  = wyv*cxs*INV2H*V1 * (r_jc ? (wz0*bz0f) : -(wz1*bz1f));
    } else if (isE){
      const float wzv = e_jc ? wz1 : wz0;
      const float cxe = wx0*kE + wx1*kF;
      const float gyw = e_wh ? (wy1*by1f) : -(wy0*by0f);
      p_gy = wzv*cxe*INV2H*gyw*V1;
    } else {
      const float wmx = m_ca? mfx : 1.f-mfx;
      const float wmy = m_cb? mfy : 1.f-mfy;
      const float wmz = m_cc? mfz : 1.f-mfz;
      p_den = wmx*wmy*wmz*V1;
    }
    if (isZ){
      const float wyv = z_jb ? wy1 : wy0;
      const float cxe2 = wx0*kZ1 + wx1*kZ2;
      const float gzw = z_wh ? (wz1*bz1f) : -(wz0*bz0f);
      p_gz += wyv*cxe2*INV2H*gzw*V2;
    }

    // ---- 64-lane butterfly reduce (all lanes end with the totals) ----
    #pragma unroll
    for (int d=1; d<64; d<<=1){
      p_sdf += __shfl_xor(p_sdf, d, 64);
      p_gx  += __shfl_xor(p_gx , d, 64);
      p_gy  += __shfl_xor(p_gy , d, 64);
      p_gz  += __shfl_xor(p_gz , d, 64);
      p_den += __shfl_xor(p_den, d, 64);
    }

    // ---- uniform epilogue ----
    const float malpha = 1.0f - __expf(-softplusf_(p_den + ACT_SHIFT_C)*DISTV);
    const float tc = vx*p_gx + vy*p_gy + vz*p_gz;
    const float icos = fminf(tc, 0.0f);
    const float e = icos*DISTV*0.5f;
    const float prev = sigmf((p_sdf - e)*SVAL);
    const float nxt  = sigmf((p_sdf + e)*SVAL);
    float alpha = (prev - nxt + 1e-5f)/(prev + 1e-5f);
    alpha = fminf(fmaxf(alpha, 0.0f), 1.0f);
    if (!(malpha >= MASK_THRES_C)) alpha = 0.0f;

    const float w1 = alpha*T1; T1 *= (1.0f - alpha);
    const float a2 = (w1 > FAST_THRES_C) ? alpha : 0.0f;
    const float wv = a2*T2;   T2 *= (1.0f - a2);
    cum += wv;
    if (wv > 0.0f && l == 0){
      int pos;
      if (emn == 1){ int p = atomicAdd(&cnt[1], 1); pos = NSAMP - 1 - p; }
      else         { pos = atomicAdd(&cnt[0], 1); }
      slist[pos] = n*NSTEPS + s;
      sw[pos] = wv;
      sgrad[pos*3+0]=p_gx; sgrad[pos*3+1]=p_gy; sgrad[pos*3+2]=p_gz;
    }
    if (T1 <= FAST_THRES_C) break;
  }
  if (l == 0){
    out[NRAYS*3 + n] = T2;
    out[NRAYS*4 + n] = 1.0f - cum;
  }
}

// ---------------- kmlp8: wave-autonomous, 8 samples/task, 4 samp x 4 out per lane ----------
#define DO4(ACC, XV) \
  ACC.x += XV.x*w0.x; ACC.y += XV.x*w0.y; ACC.z += XV.x*w0.z; ACC.w += XV.x*w0.w; \
  ACC.x += XV.y*w1.x; ACC.y += XV.y*w1.y; ACC.z += XV.y*w1.z; ACC.w += XV.y*w1.w; \
  ACC.x += XV.z*w2.x; ACC.y += XV.z*w2.y; ACC.z += XV.z*w2.z; ACC.w += XV.z*w2.w; \
  ACC.x += XV.w*w3.x; ACC.y += XV.w*w3.y; ACC.z += XV.w*w3.z; ACC.w += XV.w*w3.w;

__global__ __launch_bounds__(256, 1) void kmlp8(
  const float* __restrict__ ro, const float* __restrict__ rd,
  const float* __restrict__ vd,
  const float* __restrict__ offc, const float* __restrict__ emoc,
  const int* __restrict__ slist, const float* __restrict__ sw,
  const float* __restrict__ sgrad, const int* __restrict__ cnt,
  const float* __restrict__ W0o, const float* __restrict__ b0o,
  const float* __restrict__ W1o, const float* __restrict__ b1o,
  const float* __restrict__ W2o, const float* __restrict__ b2o,
  const float* __restrict__ W0e, const float* __restrict__ b0e,
  const float* __restrict__ W1e, const float* __restrict__ b1e,
  const float* __restrict__ W2e, const float* __restrict__ b2e,
  float* __restrict__ out)
{
  __shared__ float X [4][8][80];
  __shared__ float HA[4][8][128];
  __shared__ float HB[4][8][128];
  __shared__ float SW_[4][8];
  __shared__ int   SS_[4][8];

  const int t = threadIdx.x;
  const int wid = t >> 6;       // wave 0..3
  const int lt  = t & 63;
  const int c0 = cnt[0], c1 = cnt[1];
  const int seg1 = NSAMP - c1;
  const int totOff = c0 + c1;
  const int nOff = (totOff + 7) >> 3;
  const int nEmo = (c1 + 7) >> 3;
  const int nTask = nOff + nEmo;

  for (int task = blockIdx.x*4 + wid; task < nTask; task += gridDim.x*4) {
    const int head = (task >= nOff) ? 1 : 0;
    const int total = head ? c1 : totOff;
    const int base = (head ? (task - nOff) : task) * 8;

    const float* W0 = head ? W0e : W0o;  const float* b0 = head ? b0e : b0o;
    const float* W1 = head ? W1e : W1o;  const float* b1 = head ? b1e : b1o;
    const float* W2 = head ? W2e : W2o;  const float* b2 = head ? b2e : b2o;
    const float* cg = head ? emoc : offc;
    const float4* W04 = (const float4*)W0;
    const float4* W14 = (const float4*)W1;

    // ---- features + metadata: s = lt>>3 (8 samples), r = lt&7 (8 groups) ----
    {
      const int s = lt >> 3;
      const int r = lt & 7;
      int v = base + s;
      bool vld = (v < total);
      int vc = vld ? v : (total > 0 ? total - 1 : 0);
      int gi = head ? (seg1 + vc) : ((vc < c0) ? vc : seg1 + (vc - c0));
      const int samp = slist[gi];
      if (r == 0){
        SS_[wid][s] = samp;
        SW_[wid][s] = vld ? sw[gi] : 0.0f;
      }
      const int n = samp / NSTEPS;
      const int step = samp - n*NSTEPS;
      const float tt = NEARV + DISTV*(float)step;
      const float px = ro[n*3+0] + rd[n*3+0]*tt;
      const float py = ro[n*3+1] + rd[n*3+1]*tt;
      const float pz = ro[n*3+2] + rd[n*3+2]*tt;
      float* Xs = X[wid][s];
      if (r < 3) {
        int ix,iy,iz; float fx,fy,fz;
        tricoord(px, GG, ix, fx); tricoord(py, GG, iy, fy); tricoord(pz, GG, iz, fz);
        const float* g = cg + (size_t)r * GG3;
        const int id = (ix*GG + iy)*GG + iz;
        float v000=g[id],        v001=g[id+1];
        float v010=g[id+GG],     v011=g[id+GG+1];
        float v100=g[id+GG2],    v101=g[id+GG2+1];
        float v110=g[id+GG2+GG], v111=g[id+GG2+GG+1];
        float c00 = v000 + (v001-v000)*fz;
        float c01 = v010 + (v011-v010)*fz;
        float c10 = v100 + (v101-v100)*fz;
        float c11 = v110 + (v111-v110)*fz;
        float cl0 = c00 + (c01-c00)*fy;
        float cl1 = c10 + (c11-c10)*fy;
        Xs[r] = cl0 + (cl1-cl0)*fx;
      } else if (r == 3) {
        Xs[3] = (px+1.0f)*0.5f;
        Xs[4] = (py+1.0f)*0.5f;
        Xs[5] = (pz+1.0f)*0.5f;
        float gx = sgrad[gi*3+0], gy = sgrad[gi*3+1], gz = sgrad[gi*3+2];
        float inv = 1.0f/(sqrtf(gx*gx+gy*gy+gz*gz)+1e-5f);
        Xs[72] = gx*inv; Xs[73] = gy*inv; Xs[74] = gz*inv;
        Xs[75] = 0.0f; Xs[76] = 0.0f; Xs[77] = 0.0f; Xs[78] = 0.0f; Xs[79] = 0.0f;
      } else if (r < 7) {
        const int a = r - 4;
        const float coord = (a==0)?px:((a==1)?py:pz);
        const float rxyz = (coord+1.0f)*0.5f;
        float fr = 1.0f;
        #pragma unroll
        for (int q = 0; q < 5; q++) {
          float e = rxyz*fr; fr *= 2.0f;
          Xs[6  + a*5 + q] = __sinf(e);
          Xs[21 + a*5 + q] = __cosf(e);
        }
      } else {
        #pragma unroll
        for (int a = 0; a < 3; a++){
          const float vv = vd[n*3+a];
          float fr = 1.0f;
          #pragma unroll
          for (int q = 0; q < 4; q++) {
            float e = vv*fr; fr *= 2.0f;
            Xs[36 + a*4 + q] = e;
            Xs[48 + a*4 + q] = __sinf(e);
            Xs[60 + a*4 + q] = __cosf(e);
          }
        }
      }
    }
    // wave64 lockstep: LDS writes above ordered before reads below (same wave).

    const int sme = lt >> 5;      // half-wave: samples sme*4 .. sme*4+3
    const int l32 = lt & 31;      // outputs 4*l32 .. 4*l32+3
    const int sb = sme*4;

    // ---- layer 0: 75 -> 128 ----
    {
      const float4 bb = ((const float4*)b0)[l32];
      float4 a0 = bb, a1 = bb, a2 = bb, a3 = bb;
      const float* X0 = X[wid][sb+0];
      const float* X1 = X[wid][sb+1];
      const float* X2 = X[wid][sb+2];
      const float* X3 = X[wid][sb+3];
      #pragma unroll 2
      for (int k4 = 0; k4 < 72; k4 += 4){
        float4 w0 = W04[(k4+0)*32 + l32];
        float4 w1 = W04[(k4+1)*32 + l32];
        float4 w2 = W04[(k4+2)*32 + l32];
        float4 w3 = W04[(k4+3)*32 + l32];
        float4 x0 = *(const float4*)&X0[k4];
        float4 x1 = *(const float4*)&X1[k4];
        float4 x2 = *(const float4*)&X2[k4];
        float4 x3 = *(const float4*)&X3[k4];
        DO4(a0, x0); DO4(a1, x1); DO4(a2, x2); DO4(a3, x3);
      }
      #pragma unroll
      for (int k = 72; k < 75; k++){
        float4 w = W04[k*32 + l32];
        float x0 = X0[k], x1 = X1[k], x2 = X2[k], x3 = X3[k];
        a0.x+=x0*w.x; a0.y+=x0*w.y; a0.z+=x0*w.z; a0.w+=x0*w.w;
        a1.x+=x1*w.x; a1.y+=x1*w.y; a1.z+=x1*w.z; a1.w+=x1*w.w;
        a2.x+=x2*w.x; a2.y+=x2*w.y; a2.z+=x2*w.z; a2.w+=x2*w.w;
        a3.x+=x3*w.x; a3.y+=x3*w.y; a3.z+=x3*w.z; a3.w+=x3*w.w;
      }
      a0.x=fmaxf(a0.x,0.f); a0.y=fmaxf(a0.y,0.f); a0.z=fmaxf(a0.z,0.f); a0.w=fmaxf(a0.w,0.f);
      a1.x=fmaxf(a1.x,0.f); a1.y=fmaxf(a1.y,0.f); a1.z=fmaxf(a1.z,0.f); a1.w=fmaxf(a1.w,0.f);
      a2.x=fmaxf(a2.x,0.f); a2.y=fmaxf(a2.y,0.f); a2.z=fmaxf(a2.z,0.f); a2.w=fmaxf(a2.w,0.f);
      a3.x=fmaxf(a3.x,0.f); a3.y=fmaxf(a3.y,0.f); a3.z=fmaxf(a3.z,0.f); a3.w=fmaxf(a3.w,0.f);
      *(float4*)&HA[wid][sb+0][l32*4] = a0;
      *(float4*)&HA[wid][sb+1][l32*4] = a1;
      *(float4*)&HA[wid][sb+2][l32*4] = a2;
      *(float4*)&HA[wid][sb+3][l32*4] = a3;
    }

    // ---- layer 1: 128 -> 128 ----
    {
      const float4 bb = ((const float4*)b1)[l32];
      float4 a0 = bb, a1 = bb, a2 = bb, a3 = bb;
      const float* H0 = HA[wid][sb+0];
      const float* H1 = HA[wid][sb+1];
      const float* H2p = HA[wid][sb+2];
      const float* H3 = HA[wid][sb+3];
      #pragma unroll 2
      for (int k4 = 0; k4 < 128; k4 += 4){
        float4 w0 = W14[(k4+0)*32 + l32];
        float4 w1 = W14[(k4+1)*32 + l32];
        float4 w2 = W14[(k4+2)*32 + l32];
        float4 w3 = W14[(k4+3)*32 + l32];
        float4 x0 = *(const float4*)&H0[k4];
        float4 x1 = *(const float4*)&H1[k4];
        float4 x2 = *(const float4*)&H2p[k4];
        float4 x3 = *(const float4*)&H3[k4];
        DO4(a0, x0); DO4(a1, x1); DO4(a2, x2); DO4(a3, x3);
      }
      a0.x=fmaxf(a0.x,0.f); a0.y=fmaxf(a0.y,0.f); a0.z=fmaxf(a0.z,0.f); a0.w=fmaxf(a0.w,0.f);
      a1.x=fmaxf(a1.x,0.f); a1.y=fmaxf(a1.y,0.f); a1.z=fmaxf(a1.z,0.f); a1.w=fmaxf(a1.w,0.f);
      a2.x=fmaxf(a2.x,0.f); a2.y=fmaxf(a2.y,0.f); a2.z=fmaxf(a2.z,0.f); a2.w=fmaxf(a2.w,0.f);
      a3.x=fmaxf(a3.x,0.f); a3.y=fmaxf(a3.y,0.f); a3.z=fmaxf(a3.z,0.f); a3.w=fmaxf(a3.w,0.f);
      *(float4*)&HB[wid][sb+0][l32*4] = a0;
      *(float4*)&HB[wid][sb+1][l32*4] = a1;
      *(float4*)&HB[wid][sb+2][l32*4] = a2;
      *(float4*)&HB[wid][sb+3][l32*4] = a3;
    }

    // ---- layer 2: 128 -> 3 per sample, 32-lane shuffle reduce, atomic blend ----
    {
      float W2r[4][3];
      #pragma unroll
      for (int q = 0; q < 4; q++){
        W2r[q][0] = W2[(l32*4+q)*3+0];
        W2r[q][1] = W2[(l32*4+q)*3+1];
        W2r[q][2] = W2[(l32*4+q)*3+2];
      }
      #pragma unroll
      for (int m = 0; m < 4; m++){
        const int s = sb + m;
        float4 h = *(const float4*)&HB[wid][s][l32*4];
        float c0v = h.x*W2r[0][0] + h.y*W2r[1][0] + h.z*W2r[2][0] + h.w*W2r[3][0];
        float c1v = h.x*W2r[0][1] + h.y*W2r[1][1] + h.z*W2r[2][1] + h.w*W2r[3][1];
        float c2v = h.x*W2r[0][2] + h.y*W2r[1][2] + h.z*W2r[2][2] + h.w*W2r[3][2];
        #pragma unroll
        for (int d=16; d>=1; d>>=1){
          c0v += __shfl_down(c0v, d, 32);
          c1v += __shfl_down(c1v, d, 32);
          c2v += __shfl_down(c2v, d, 32);
        }
        if (l32 == 0){
          float w = SW_[wid][s];
          if (w > 0.0f){
            int n2 = SS_[wid][s] / NSTEPS;
            atomicAdd(&out[n2*3+0], w * sigmf(c0v + b2[0]));
            atomicAdd(&out[n2*3+1], w * sigmf(c1v + b2[1]));
            atomicAdd(&out[n2*3+2], w * sigmf(c2v + b2[2]));
          }
        }
      }
    }
  }
}

extern "C" void kernel_launch(void* const* d_in, const int* in_sizes, int n_in,
                              void* d_out, int out_size, void* d_ws, size_t ws_size,
                              hipStream_t stream) {
  const float* ro    = (const float*)d_in[0];
  const float* rd    = (const float*)d_in[1];
  const float* vd    = (const float*)d_in[2];
  const int*   em    = (const int*)d_in[3];
  const float* sdfg  = (const float*)d_in[4];
  const float* maskg = (const float*)d_in[5];
  const float* offc  = (const float*)d_in[6];
  const float* emoc  = (const float*)d_in[7];
  const float* W0o = (const float*)d_in[8];
  const float* b0o = (const float*)d_in[9];
  const float* W1o = (const float*)d_in[10];
  const float* b1o = (const float*)d_in[11];
  const float* W2o = (const float*)d_in[12];
  const float* b2o = (const float*)d_in[13];
  const float* W0e = (const float*)d_in[14];
  const float* b0e = (const float*)d_in[15];
  const float* W1e = (const float*)d_in[16];
  const float* b1e = (const float*)d_in[17];
  const float* W2e = (const float*)d_in[18];
  const float* b2e = (const float*)d_in[19];

  float* out = (float*)d_out;
  float* ws  = (float*)d_ws;
  float* Yb    = ws;                         // GG3 (yz-smoothed)
  float* swb   = ws + GG3;                   // NSAMP
  float* sgradb= swb + NSAMP;                // 3*NSAMP
  int*   slist = (int*)(sgradb + 3*(size_t)NSAMP);  // NSAMP
  int*   cnt   = slist + NSAMP;              // 2

  ksmooth_yz<<<GG*25, 256, 0, stream>>>(sdfg, Yb, out, cnt);

  kmarch_wave<<<NRAYS/4, 256, 0, stream>>>(ro, rd, vd, em, maskg, Yb,
                                           slist, swb, sgradb, cnt, out);

  kmlp8<<<256, 256, 0, stream>>>(ro, rd, vd, offc, emoc,
                                 slist, swb, sgradb, cnt,
                                 W0o,b0o,W1o,b1o,W2o,b2o,
                                 W0e,b0e,W1e,b1e,W2e,b2e, out);
}

// Round 15
// 54.160 us; speedup vs baseline: 1.6200x; 1.6200x over previous
//
#include <hip/hip_runtime.h>

#define NRAYS 4096
#define NSTEPS 160
#define NSAMP (NRAYS*NSTEPS)
#define GG 160
#define GG2 (GG*GG)
#define GG3 (GG*GG2)
#define GM 80
#define GM2 (GM*GM)

#define NEARV 0.05f
#define DISTV 0.00625f
#define SVAL 80.0f
#define ACT_SHIFT_C (-9.2102403669758813f)
#define INV2H 40.0f          // 1/(2*VOXEL_SIZE)
#define MASK_THRES_C 1e-3f
#define FAST_THRES_C 1e-7f

// normalized 5-tap gaussian, sigma=1
#define KW0 0.05448868454964295f
#define KW1 0.24420134200323332f
#define KW2 0.40261994689424750f

__device__ __forceinline__ float sigmf(float x){ return 1.0f/(1.0f+__expf(-x)); }
__device__ __forceinline__ float softplusf_(float x){ return (x>20.0f)? x : log1pf(__expf(x)); }

__device__ __forceinline__ void tricoord(float p, int Gx, int& i0, float& fr){
  float u = (p + 1.0f)*0.5f*(float)(Gx-1);
  u = fminf(fmaxf(u, 0.0f), (float)(Gx-1));
  int i = (int)floorf(u);
  i = min(max(i,0), Gx-2);
  i0 = i; fr = u - (float)i;
}

// ---------------- fused y+z gaussian passes (zero-pad SAME), LDS tiled ----------------
__global__ __launch_bounds__(256) void ksmooth_yz(const float* __restrict__ in, float* __restrict__ out,
                                                  float* __restrict__ outbuf, int* __restrict__ cnt){
  __shared__ float S[36][37];
  __shared__ float Tz[36][33];
  const int bx = blockIdx.x;          // 160 * 25
  const int t = threadIdx.x;
  if (bx == 0){
    for (int i = t; i < NRAYS*3; i += 256) outbuf[i] = 0.0f;
    if (t < 2) cnt[t] = 0;
  }
  const int x  = bx / 25;
  const int tile = bx % 25;
  const int Y0 = (tile/5)*32, Z0 = (tile%5)*32;
  const float kw[5] = {KW0,KW1,KW2,KW1,KW0};
  for (int i = t; i < 36*36; i += 256){
    int r = i/36, c = i - (i/36)*36;
    int y = Y0 + r - 2, z = Z0 + c - 2;
    float v = 0.0f;
    if (y>=0 && y<GG && z>=0 && z<GG) v = in[(x*GG+y)*GG+z];
    S[r][c] = v;
  }
  __syncthreads();
  for (int i = t; i < 36*32; i += 256){
    int r = i >> 5, c = i & 31;
    float acc = 0.f;
    #pragma unroll
    for (int d=0; d<5; d++) acc += kw[d]*S[r][c+d];
    Tz[r][c] = acc;
  }
  __syncthreads();
  for (int i = t; i < 32*32; i += 256){
    int yy = i >> 5, c = i & 31;
    float acc = 0.f;
    #pragma unroll
    for (int d=0; d<5; d++) acc += kw[d]*Tz[yy+d][c];
    out[(x*GG + Y0+yy)*GG + Z0 + c] = acc;
  }
}

// ---------------- serial per-ray march on yz-smoothed grid, x-conv on the fly ----------------
// Compacted list PARTITIONED by em mode: em=0 ascend from 0 (cnt[0]), em=1 descend
// from NSAMP (cnt[1]). Early break exact: once T1 <= 1e-7 all later keep1 fail.
__global__ __launch_bounds__(64) void kmarch(
  const float* __restrict__ ro, const float* __restrict__ rd,
  const float* __restrict__ vd, const int* __restrict__ em,
  const float* __restrict__ maskg, const float* __restrict__ Y,
  int* __restrict__ slist, float* __restrict__ sw, float* __restrict__ sgrad,
  int* __restrict__ cnt, float* __restrict__ out)
{
  int n = blockIdx.x*64 + threadIdx.x;
  if (n >= NRAYS) return;
  const float ox=ro[n*3+0], oy=ro[n*3+1], oz=ro[n*3+2];
  const float dx=rd[n*3+0], dy=rd[n*3+1], dz=rd[n*3+2];
  const float vx=vd[n*3+0], vy=vd[n*3+1], vz=vd[n*3+2];
  const int emn = em[n];
  const float kwc[5] = {KW0,KW1,KW2,KW1,KW0};
  float T1=1.0f, T2=1.0f, cum=0.0f;
  for (int s=0; s<NSTEPS; s++){
    float tt = NEARV + DISTV*(float)s;
    float px = ox + dx*tt, py = oy + dy*tt, pz = oz + dz*tt;

    int mx,my,mz; float mfx,mfy,mfz;
    tricoord(px, GM, mx, mfx); tricoord(py, GM, my, mfy); tricoord(pz, GM, mz, mfz);
    int mid = (mx*GM + my)*GM + mz;
    float d000=maskg[mid],        d001=maskg[mid+1];
    float d010=maskg[mid+GM],     d011=maskg[mid+GM+1];
    float d100=maskg[mid+GM2],    d101=maskg[mid+GM2+1];
    float d110=maskg[mid+GM2+GM], d111=maskg[mid+GM2+GM+1];
    float m00 = d000 + (d001-d000)*mfz;
    float m01 = d010 + (d011-d010)*mfz;
    float m10 = d100 + (d101-d100)*mfz;
    float m11 = d110 + (d111-d110)*mfz;
    float m0 = m00 + (m01-m00)*mfy;
    float m1 = m10 + (m11-m10)*mfy;
    float dens = m0 + (m1-m0)*mfx;
    float malpha = 1.0f - __expf(-softplusf_(dens + ACT_SHIFT_C)*DISTV);

    int ix,iy,iz; float fx,fy,fz;
    tricoord(px, GG, ix, fx); tricoord(py, GG, iy, fy); tricoord(pz, GG, iz, fz);

    float R[2][2][8];
    #pragma unroll
    for (int jb=0;jb<2;jb++)
      #pragma unroll
      for (int jc=0;jc<2;jc++)
        #pragma unroll
        for (int j=0;j<8;j++){
          int a = ix-3+j;
          R[jb][jc][j] = (a>=0 && a<GG) ? Y[(a*GG + iy+jb)*GG + iz+jc] : 0.0f;
        }
    const bool hasym = (iy>=1), hasyp = (iy<=GG-3);
    const bool haszm = (iz>=1), haszp = (iz<=GG-3);
    float Eym[2][6], Eyp[2][6], Ezm[2][6], Ezp[2][6];
    #pragma unroll
    for (int jc=0;jc<2;jc++)
      #pragma unroll
      for (int j=0;j<6;j++){
        int a = ix-2+j;
        bool ax = (a>=0 && a<GG);
        Eym[jc][j] = (hasym && ax) ? Y[(a*GG + iy-1)*GG + iz+jc] : 0.0f;
        Eyp[jc][j] = (hasyp && ax) ? Y[(a*GG + iy+2)*GG + iz+jc] : 0.0f;
      }
    #pragma unroll
    for (int jb=0;jb<2;jb++)
      #pragma unroll
      for (int j=0;j<6;j++){
        int a = ix-2+j;
        bool ax = (a>=0 && a<GG);
        Ezm[jb][j] = (haszm && ax) ? Y[(a*GG + iy+jb)*GG + iz-1] : 0.0f;
        Ezp[jb][j] = (haszp && ax) ? Y[(a*GG + iy+jb)*GG + iz+2] : 0.0f;
      }

    float sdf=0.0f, gx=0.0f, gy=0.0f, gz=0.0f;
    #pragma unroll
    for (int ja=0;ja<2;ja++){
      #pragma unroll
      for (int jb=0;jb<2;jb++){
        #pragma unroll
        for (int jc=0;jc<2;jc++){
          float w = (ja?fx:1.0f-fx)*(jb?fy:1.0f-fy)*(jc?fz:1.0f-fz);
          const float* r = R[jb][jc];
          float s0=0.0f;
          #pragma unroll
          for (int t2=0;t2<5;t2++) s0 += kwc[t2]*r[ja+1+t2];
          sdf += w*s0;
          int a = ix+ja, b = iy+jb, c = iz+jc;
          if (a>=1 && a<=GG-2){
            float sp=0.0f, sm=0.0f;
            #pragma unroll
            for (int t2=0;t2<5;t2++){ sp += kwc[t2]*r[ja+2+t2]; sm += kwc[t2]*r[ja+t2]; }
            gx += w*INV2H*(sp-sm);
          }
          if (b>=1 && b<=GG-2){
            float acc=0.0f;
            if (jb==0){
              const float* up = R[1][jc];
              const float* dn = Eym[jc];
              #pragma unroll
              for (int t2=0;t2<5;t2++) acc += kwc[t2]*(up[ja+1+t2] - dn[ja+t2]);
            } else {
              const float* up = Eyp[jc];
              const float* dn = R[0][jc];
              #pragma unroll
              for (int t2=0;t2<5;t2++) acc += kwc[t2]*(up[ja+t2] - dn[ja+1+t2]);
            }
            gy += w*INV2H*acc;
          }
          if (c>=1 && c<=GG-2){
            float acc=0.0f;
            if (jc==0){
              const float* up = R[jb][1];
              const float* dn = Ezm[jb];
              #pragma unroll
              for (int t2=0;t2<5;t2++) acc += kwc[t2]*(up[ja+1+t2] - dn[ja+t2]);
            } else {
              const float* up = Ezp[jb];
              const float* dn = R[jb][0];
              #pragma unroll
              for (int t2=0;t2<5;t2++) acc += kwc[t2]*(up[ja+t2] - dn[ja+1+t2]);
            }
            gz += w*INV2H*acc;
          }
        }
      }
    }

    float tc = vx*gx + vy*gy + vz*gz;
    float icos = fminf(tc, 0.0f);
    float e = icos*DISTV*0.5f;
    float prev = sigmf((sdf - e)*SVAL);
    float nxt  = sigmf((sdf + e)*SVAL);
    float alpha = (prev - nxt + 1e-5f)/(prev + 1e-5f);
    alpha = fminf(fmaxf(alpha, 0.0f), 1.0f);
    if (!(malpha >= MASK_THRES_C)) alpha = 0.0f;

    float w1 = alpha*T1; T1 *= (1.0f - alpha);
    float a2 = (w1 > FAST_THRES_C) ? alpha : 0.0f;
    float wv = a2*T2;   T2 *= (1.0f - a2);
    cum += wv;
    if (wv > 0.0f){
      int pos;
      if (emn == 1){ int p = atomicAdd(&cnt[1], 1); pos = NSAMP - 1 - p; }
      else         { pos = atomicAdd(&cnt[0], 1); }
      slist[pos] = n*NSTEPS + s;
      sw[pos] = wv;
      sgrad[pos*3+0]=gx; sgrad[pos*3+1]=gy; sgrad[pos*3+2]=gz;
    }
    if (T1 <= FAST_THRES_C) break;
  }
  out[NRAYS*3 + n] = T2;
  out[NRAYS*4 + n] = 1.0f - cum;
}

// ---------------- kmlp8: wave-autonomous, 8 samples/task, 4 samp x 4 out per lane ----------
#define DO4(ACC, XV) \
  ACC.x += XV.x*w0.x; ACC.y += XV.x*w0.y; ACC.z += XV.x*w0.z; ACC.w += XV.x*w0.w; \
  ACC.x += XV.y*w1.x; ACC.y += XV.y*w1.y; ACC.z += XV.y*w1.z; ACC.w += XV.y*w1.w; \
  ACC.x += XV.z*w2.x; ACC.y += XV.z*w2.y; ACC.z += XV.z*w2.z; ACC.w += XV.z*w2.w; \
  ACC.x += XV.w*w3.x; ACC.y += XV.w*w3.y; ACC.z += XV.w*w3.z; ACC.w += XV.w*w3.w;

__global__ __launch_bounds__(256, 1) void kmlp8(
  const float* __restrict__ ro, const float* __restrict__ rd,
  const float* __restrict__ vd,
  const float* __restrict__ offc, const float* __restrict__ emoc,
  const int* __restrict__ slist, const float* __restrict__ sw,
  const float* __restrict__ sgrad, const int* __restrict__ cnt,
  const float* __restrict__ W0o, const float* __restrict__ b0o,
  const float* __restrict__ W1o, const float* __restrict__ b1o,
  const float* __restrict__ W2o, const float* __restrict__ b2o,
  const float* __restrict__ W0e, const float* __restrict__ b0e,
  const float* __restrict__ W1e, const float* __restrict__ b1e,
  const float* __restrict__ W2e, const float* __restrict__ b2e,
  float* __restrict__ out)
{
  __shared__ float X [4][8][80];
  __shared__ float HA[4][8][128];
  __shared__ float HB[4][8][128];
  __shared__ float SW_[4][8];
  __shared__ int   SS_[4][8];

  const int t = threadIdx.x;
  const int wid = t >> 6;       // wave 0..3
  const int lt  = t & 63;
  const int c0 = cnt[0], c1 = cnt[1];
  const int seg1 = NSAMP - c1;
  const int totOff = c0 + c1;
  const int nOff = (totOff + 7) >> 3;
  const int nEmo = (c1 + 7) >> 3;
  const int nTask = nOff + nEmo;

  for (int task = blockIdx.x*4 + wid; task < nTask; task += gridDim.x*4) {
    const int head = (task >= nOff) ? 1 : 0;
    const int total = head ? c1 : totOff;
    const int base = (head ? (task - nOff) : task) * 8;

    const float* W0 = head ? W0e : W0o;  const float* b0 = head ? b0e : b0o;
    const float* W1 = head ? W1e : W1o;  const float* b1 = head ? b1e : b1o;
    const float* W2 = head ? W2e : W2o;  const float* b2 = head ? b2e : b2o;
    const float* cg = head ? emoc : offc;
    const float4* W04 = (const float4*)W0;
    const float4* W14 = (const float4*)W1;

    // ---- features + metadata: s = lt>>3 (8 samples), r = lt&7 (8 groups) ----
    {
      const int s = lt >> 3;
      const int r = lt & 7;
      int v = base + s;
      bool vld = (v < total);
      int vc = vld ? v : (total > 0 ? total - 1 : 0);
      int gi = head ? (seg1 + vc) : ((vc < c0) ? vc : seg1 + (vc - c0));
      const int samp = slist[gi];
      if (r == 0){
        SS_[wid][s] = samp;
        SW_[wid][s] = vld ? sw[gi] : 0.0f;
      }
      const int n = samp / NSTEPS;
      const int step = samp - n*NSTEPS;
      const float tt = NEARV + DISTV*(float)step;
      const float px = ro[n*3+0] + rd[n*3+0]*tt;
      const float py = ro[n*3+1] + rd[n*3+1]*tt;
      const float pz = ro[n*3+2] + rd[n*3+2]*tt;
      float* Xs = X[wid][s];
      if (r < 3) {
        int ix,iy,iz; float fx,fy,fz;
        tricoord(px, GG, ix, fx); tricoord(py, GG, iy, fy); tricoord(pz, GG, iz, fz);
        const float* g = cg + (size_t)r * GG3;
        const int id = (ix*GG + iy)*GG + iz;
        float v000=g[id],        v001=g[id+1];
        float v010=g[id+GG],     v011=g[id+GG+1];
        float v100=g[id+GG2],    v101=g[id+GG2+1];
        float v110=g[id+GG2+GG], v111=g[id+GG2+GG+1];
        float c00 = v000 + (v001-v000)*fz;
        float c01 = v010 + (v011-v010)*fz;
        float c10 = v100 + (v101-v100)*fz;
        float c11 = v110 + (v111-v110)*fz;
        float cl0 = c00 + (c01-c00)*fy;
        float cl1 = c10 + (c11-c10)*fy;
        Xs[r] = cl0 + (cl1-cl0)*fx;
      } else if (r == 3) {
        Xs[3] = (px+1.0f)*0.5f;
        Xs[4] = (py+1.0f)*0.5f;
        Xs[5] = (pz+1.0f)*0.5f;
        float gx = sgrad[gi*3+0], gy = sgrad[gi*3+1], gz = sgrad[gi*3+2];
        float inv = 1.0f/(sqrtf(gx*gx+gy*gy+gz*gz)+1e-5f);
        Xs[72] = gx*inv; Xs[73] = gy*inv; Xs[74] = gz*inv;
        Xs[75] = 0.0f; Xs[76] = 0.0f; Xs[77] = 0.0f; Xs[78] = 0.0f; Xs[79] = 0.0f;
      } else if (r < 7) {
        const int a = r - 4;
        const float coord = (a==0)?px:((a==1)?py:pz);
        const float rxyz = (coord+1.0f)*0.5f;
        float fr = 1.0f;
        #pragma unroll
        for (int q = 0; q < 5; q++) {
          float e = rxyz*fr; fr *= 2.0f;
          Xs[6  + a*5 + q] = __sinf(e);
          Xs[21 + a*5 + q] = __cosf(e);
        }
      } else {
        #pragma unroll
        for (int a = 0; a < 3; a++){
          const float vv = vd[n*3+a];
          float fr = 1.0f;
          #pragma unroll
          for (int q = 0; q < 4; q++) {
            float e = vv*fr; fr *= 2.0f;
            Xs[36 + a*4 + q] = e;
            Xs[48 + a*4 + q] = __sinf(e);
            Xs[60 + a*4 + q] = __cosf(e);
          }
        }
      }
    }
    // wave64 lockstep: LDS writes above ordered before reads below (same wave).

    const int sme = lt >> 5;      // half-wave: samples sme*4 .. sme*4+3
    const int l32 = lt & 31;      // outputs 4*l32 .. 4*l32+3
    const int sb = sme*4;

    // ---- layer 0: 75 -> 128 ----
    {
      const float4 bb = ((const float4*)b0)[l32];
      float4 a0 = bb, a1 = bb, a2 = bb, a3 = bb;
      const float* X0 = X[wid][sb+0];
      const float* X1 = X[wid][sb+1];
      const float* X2 = X[wid][sb+2];
      const float* X3 = X[wid][sb+3];
      #pragma unroll 2
      for (int k4 = 0; k4 < 72; k4 += 4){
        float4 w0 = W04[(k4+0)*32 + l32];
        float4 w1 = W04[(k4+1)*32 + l32];
        float4 w2 = W04[(k4+2)*32 + l32];
        float4 w3 = W04[(k4+3)*32 + l32];
        float4 x0 = *(const float4*)&X0[k4];
        float4 x1 = *(const float4*)&X1[k4];
        float4 x2 = *(const float4*)&X2[k4];
        float4 x3 = *(const float4*)&X3[k4];
        DO4(a0, x0); DO4(a1, x1); DO4(a2, x2); DO4(a3, x3);
      }
      #pragma unroll
      for (int k = 72; k < 75; k++){
        float4 w = W04[k*32 + l32];
        float x0 = X0[k], x1 = X1[k], x2 = X2[k], x3 = X3[k];
        a0.x+=x0*w.x; a0.y+=x0*w.y; a0.z+=x0*w.z; a0.w+=x0*w.w;
        a1.x+=x1*w.x; a1.y+=x1*w.y; a1.z+=x1*w.z; a1.w+=x1*w.w;
        a2.x+=x2*w.x; a2.y+=x2*w.y; a2.z+=x2*w.z; a2.w+=x2*w.w;
        a3.x+=x3*w.x; a3.y+=x3*w.y; a3.z+=x3*w.z; a3.w+=x3*w.w;
      }
      a0.x=fmaxf(a0.x,0.f); a0.y=fmaxf(a0.y,0.f); a0.z=fmaxf(a0.z,0.f); a0.w=fmaxf(a0.w,0.f);
      a1.x=fmaxf(a1.x,0.f); a1.y=fmaxf(a1.y,0.f); a1.z=fmaxf(a1.z,0.f); a1.w=fmaxf(a1.w,0.f);
      a2.x=fmaxf(a2.x,0.f); a2.y=fmaxf(a2.y,0.f); a2.z=fmaxf(a2.z,0.f); a2.w=fmaxf(a2.w,0.f);
      a3.x=fmaxf(a3.x,0.f); a3.y=fmaxf(a3.y,0.f); a3.z=fmaxf(a3.z,0.f); a3.w=fmaxf(a3.w,0.f);
      *(float4*)&HA[wid][sb+0][l32*4] = a0;
      *(float4*)&HA[wid][sb+1][l32*4] = a1;
      *(float4*)&HA[wid][sb+2][l32*4] = a2;
      *(float4*)&HA[wid][sb+3][l32*4] = a3;
    }

    // ---- layer 1: 128 -> 128 ----
    {
      const float4 bb = ((const float4*)b1)[l32];
      float4 a0 = bb, a1 = bb, a2 = bb, a3 = bb;
      const float* H0 = HA[wid][sb+0];
      const float* H1 = HA[wid][sb+1];
      const float* H2p = HA[wid][sb+2];
      const float* H3 = HA[wid][sb+3];
      #pragma unroll 2
      for (int k4 = 0; k4 < 128; k4 += 4){
        float4 w0 = W14[(k4+0)*32 + l32];
        float4 w1 = W14[(k4+1)*32 + l32];
        float4 w2 = W14[(k4+2)*32 + l32];
        float4 w3 = W14[(k4+3)*32 + l32];
        float4 x0 = *(const float4*)&H0[k4];
        float4 x1 = *(const float4*)&H1[k4];
        float4 x2 = *(const float4*)&H2p[k4];
        float4 x3 = *(const float4*)&H3[k4];
        DO4(a0, x0); DO4(a1, x1); DO4(a2, x2); DO4(a3, x3);
      }
      a0.x=fmaxf(a0.x,0.f); a0.y=fmaxf(a0.y,0.f); a0.z=fmaxf(a0.z,0.f); a0.w=fmaxf(a0.w,0.f);
      a1.x=fmaxf(a1.x,0.f); a1.y=fmaxf(a1.y,0.f); a1.z=fmaxf(a1.z,0.f); a1.w=fmaxf(a1.w,0.f);
      a2.x=fmaxf(a2.x,0.f); a2.y=fmaxf(a2.y,0.f); a2.z=fmaxf(a2.z,0.f); a2.w=fmaxf(a2.w,0.f);
      a3.x=fmaxf(a3.x,0.f); a3.y=fmaxf(a3.y,0.f); a3.z=fmaxf(a3.z,0.f); a3.w=fmaxf(a3.w,0.f);
      *(float4*)&HB[wid][sb+0][l32*4] = a0;
      *(float4*)&HB[wid][sb+1][l32*4] = a1;
      *(float4*)&HB[wid][sb+2][l32*4] = a2;
      *(float4*)&HB[wid][sb+3][l32*4] = a3;
    }

    // ---- layer 2: 128 -> 3 per sample, 32-lane shuffle reduce, atomic blend ----
    {
      float W2r[4][3];
      #pragma unroll
      for (int q = 0; q < 4; q++){
        W2r[q][0] = W2[(l32*4+q)*3+0];
        W2r[q][1] = W2[(l32*4+q)*3+1];
        W2r[q][2] = W2[(l32*4+q)*3+2];
      }
      #pragma unroll
      for (int m = 0; m < 4; m++){
        const int s = sb + m;
        float4 h = *(const float4*)&HB[wid][s][l32*4];
        float c0v = h.x*W2r[0][0] + h.y*W2r[1][0] + h.z*W2r[2][0] + h.w*W2r[3][0];
        float c1v = h.x*W2r[0][1] + h.y*W2r[1][1] + h.z*W2r[2][1] + h.w*W2r[3][1];
        float c2v = h.x*W2r[0][2] + h.y*W2r[1][2] + h.z*W2r[2][2] + h.w*W2r[3][2];
        #pragma unroll
        for (int d=16; d>=1; d>>=1){
          c0v += __shfl_down(c0v, d, 32);
          c1v += __shfl_down(c1v, d, 32);
          c2v += __shfl_down(c2v, d, 32);
        }
        if (l32 == 0){
          float w = SW_[wid][s];
          if (w > 0.0f){
            int n2 = SS_[wid][s] / NSTEPS;
            atomicAdd(&out[n2*3+0], w * sigmf(c0v + b2[0]));
            atomicAdd(&out[n2*3+1], w * sigmf(c1v + b2[1]));
            atomicAdd(&out[n2*3+2], w * sigmf(c2v + b2[2]));
          }
        }
      }
    }
  }
}

extern "C" void kernel_launch(void* const* d_in, const int* in_sizes, int n_in,
                              void* d_out, int out_size, void* d_ws, size_t ws_size,
                              hipStream_t stream) {
  const float* ro    = (const float*)d_in[0];
  const float* rd    = (const float*)d_in[1];
  const float* vd    = (const float*)d_in[2];
  const int*   em    = (const int*)d_in[3];
  const float* sdfg  = (const float*)d_in[4];
  const float* maskg = (const float*)d_in[5];
  const float* offc  = (const float*)d_in[6];
  const float* emoc  = (const float*)d_in[7];
  const float* W0o = (const float*)d_in[8];
  const float* b0o = (const float*)d_in[9];
  const float* W1o = (const float*)d_in[10];
  const float* b1o = (const float*)d_in[11];
  const float* W2o = (const float*)d_in[12];
  const float* b2o = (const float*)d_in[13];
  const float* W0e = (const float*)d_in[14];
  const float* b0e = (const float*)d_in[15];
  const float* W1e = (const float*)d_in[16];
  const float* b1e = (const float*)d_in[17];
  const float* W2e = (const float*)d_in[18];
  const float* b2e = (const float*)d_in[19];

  float* out = (float*)d_out;
  float* ws  = (float*)d_ws;
  float* Yb    = ws;                         // GG3 (yz-smoothed)
  float* swb   = ws + GG3;                   // NSAMP
  float* sgradb= swb + NSAMP;                // 3*NSAMP
  int*   slist = (int*)(sgradb + 3*(size_t)NSAMP);  // NSAMP
  int*   cnt   = slist + NSAMP;              // 2

  ksmooth_yz<<<GG*25, 256, 0, stream>>>(sdfg, Yb, out, cnt);

  kmarch<<<NRAYS/64, 64, 0, stream>>>(ro, rd, vd, em, maskg, Yb,
                                      slist, swb, sgradb, cnt, out);

  kmlp8<<<256, 256, 0, stream>>>(ro, rd, vd, offc, emoc,
                                 slist, swb, sgradb, cnt,
                                 W0o,b0o,W1o,b1o,W2o,b2o,
                                 W0e,b0e,W1e,b1e,W2e,b2e, out);
}